// Round 17
// baseline (257.651 us; speedup 1.0000x reference)
//
#include <hip/hip_runtime.h>
#include <hip/hip_fp16.h>

#define NNODES 100000
#define NEDGES 3200000
#define FEAT 32
#define NITER 5
#define NF (NNODES * FEAT)

// bucket partition
#define BUCK_SH 8
#define BUCK_SZ 256                    // dsts per bucket
#define NBK 391                        // ceil(100000/256)
#define CHUNKF 4096                    // edges per ws/fill block
#define NBF 782                        // 782*4096 = 3,203,072 >= NEDGES
#define NT (NBF * NBK)                 // 305,762 matrix elements
#define NTB 299                        // ceil(NT/1024)

// ---- pass A (fused): packed payload + bucket id + per-block histogram + masked-sum ----
__global__ void ws_kernel(const int* __restrict__ edge_index,
                          const int* __restrict__ edge_mask,
                          const float* __restrict__ edge_scale,
                          const float* __restrict__ pert_mask,
                          const float* __restrict__ edge_weight,
                          int2* __restrict__ pay,
                          unsigned short* __restrict__ bkt,
                          int* __restrict__ M,
                          float* __restrict__ S_part) {
    __shared__ int h[NBK];
    __shared__ float sred[256];
    const int b = blockIdx.x;
    for (int k = threadIdx.x; k < NBK; k += 256) h[k] = 0;
    __syncthreads();
    const int base = b * CHUNKF;
    float ms = 0.0f;
    for (int it = 0; it < CHUNKF / 256; ++it) {
        const int e = base + it * 256 + threadIdx.x;
        if (e < NEDGES) {
            const int m = edge_mask[e];
            const float w = (edge_weight[e] * (1.0f - pert_mask[e]) + pert_mask[e]) * edge_scale[e];
            const int src = edge_index[e];
            const int dst = edge_index[NEDGES + e];
            pay[e] = make_int2(src | ((dst & (BUCK_SZ - 1)) << 20), __float_as_int(w));
            if (m) {
                bkt[e] = (unsigned short)(dst >> BUCK_SH);
                atomicAdd(&h[dst >> BUCK_SH], 1);
            } else {
                bkt[e] = (unsigned short)0xFFFFu;
                ms += w;
            }
        }
    }
    sred[threadIdx.x] = ms;
    __syncthreads();                      // also orders all h[] atomics before M write
    for (int off = 128; off; off >>= 1) {
        if (threadIdx.x < off) sred[threadIdx.x] += sred[threadIdx.x + off];
        __syncthreads();
    }
    if (threadIdx.x == 0) S_part[b] = sred[0];
    for (int k = threadIdx.x; k < NBK; k += 256) M[b * NBK + k] = h[k];
}

__global__ void sreduce_kernel(const float* __restrict__ S_part, float* __restrict__ S) {
    __shared__ float s[1024];
    float a = 0.0f;
    for (int i = threadIdx.x; i < NBF; i += 1024) a += S_part[i];
    s[threadIdx.x] = a;
    __syncthreads();
    for (int off = 512; off; off >>= 1) {
        if (threadIdx.x < off) s[threadIdx.x] += s[threadIdx.x + off];
        __syncthreads();
    }
    if (threadIdx.x == 0) *S = s[0];
}

// ---- 3-stage exclusive scan over M in bucket-major (transposed) order ----
__global__ void tscan1_kernel(const int* __restrict__ M, int* __restrict__ tb) {
    __shared__ int s[1024];
    const int i = blockIdx.x * 1024 + threadIdx.x;
    int v = 0;
    if (i < NT) v = M[(i % NBF) * NBK + (i / NBF)];
    s[threadIdx.x] = v;
    __syncthreads();
    for (int off = 512; off; off >>= 1) {
        if (threadIdx.x < off) s[threadIdx.x] += s[threadIdx.x + off];
        __syncthreads();
    }
    if (threadIdx.x == 0) tb[blockIdx.x] = s[0];
}

__global__ void tscan2_kernel(const int* __restrict__ tb, int* __restrict__ tboff,
                              int* __restrict__ bucket_base) {
    __shared__ int s[512];
    const int tid = threadIdx.x;
    int v = (tid < NTB) ? tb[tid] : 0;
    s[tid] = v;
    __syncthreads();
    for (int off = 1; off < 512; off <<= 1) {
        int t = (tid >= off) ? s[tid - off] : 0;
        __syncthreads();
        s[tid] += t;
        __syncthreads();
    }
    if (tid < NTB) tboff[tid] = s[tid] - v;     // exclusive
    if (tid == 511) bucket_base[NBK] = s[511];  // total unmasked edges
}

__global__ void tscan3_kernel(const int* __restrict__ M, const int* __restrict__ tboff,
                              int* __restrict__ scanT, int* __restrict__ bucket_base) {
    __shared__ int s[1024];
    const int tid = threadIdx.x;
    const int i = blockIdx.x * 1024 + tid;
    int v = 0;
    if (i < NT) v = M[(i % NBF) * NBK + (i / NBF)];
    s[tid] = v;
    __syncthreads();
    for (int off = 1; off < 1024; off <<= 1) {
        int t = (tid >= off) ? s[tid - off] : 0;
        __syncthreads();
        s[tid] += t;
        __syncthreads();
    }
    if (i < NT) {
        const int excl = tboff[blockIdx.x] + s[tid] - v;
        scanT[i] = excl;
        if (i % NBF == 0) bucket_base[i / NBF] = excl;
    }
}

// ---- fill: scatter packed payload to matrix offsets; no global atomics ----
__global__ void fill782_kernel(const int2* __restrict__ pay,
                               const unsigned short* __restrict__ bkt,
                               const int* __restrict__ scanT,
                               int2* __restrict__ e8tmp) {
    __shared__ int off[NBK];
    const int b = blockIdx.x;
    for (int k = threadIdx.x; k < NBK; k += 256) off[k] = scanT[k * NBF + b];
    __syncthreads();
    const int base = b * CHUNKF;
    for (int it = 0; it < CHUNKF / 256; ++it) {
        const int e = base + it * 256 + threadIdx.x;
        if (e < NEDGES) {
            const unsigned short k = bkt[e];
            if (k != 0xFFFFu) {
                const int pos = atomicAdd(&off[k], 1);
                e8tmp[pos] = pay[e];
            }
        }
    }
}

// ---- bucket sort: one block per bucket; LDS counting sort by local dst ----
// emits final dst-sorted PACKED e4 (src<<15 | fp16(w) sans sign) and row_ptr.
// w >= 0 always ((ew*(1-pm)+pm)*es, all operands in [0,1)) so the sign bit is free.
__global__ void bsort_kernel(const int2* __restrict__ e8tmp,
                             const int* __restrict__ bucket_base,
                             unsigned* __restrict__ e4,
                             int* __restrict__ row_ptr) {
    __shared__ int h[BUCK_SZ];
    __shared__ int s[BUCK_SZ];
    __shared__ int woff[BUCK_SZ];
    const int k = blockIdx.x;
    const int tid = threadIdx.x;
    const int base0 = bucket_base[k];
    const int cnt = bucket_base[k + 1] - base0;
    h[tid] = 0;
    __syncthreads();
    for (int i = tid; i < cnt; i += 256) {
        const int dstl = e8tmp[base0 + i].x >> 20;   // bits 20..27 (src < 2^17)
        atomicAdd(&h[dstl], 1);
    }
    __syncthreads();
    s[tid] = h[tid];
    __syncthreads();
    for (int off = 1; off < BUCK_SZ; off <<= 1) {
        int t = (tid >= off) ? s[tid - off] : 0;
        __syncthreads();
        s[tid] += t;
        __syncthreads();
    }
    {
        const int excl = s[tid] - h[tid];
        const int d = k * BUCK_SZ + tid;
        if (d < NNODES) row_ptr[d] = base0 + excl;
        woff[tid] = excl;
    }
    if (k == NBK - 1 && tid == 0) row_ptr[NNODES] = bucket_base[NBK];
    __syncthreads();
    for (int i = tid; i < cnt; i += 256) {
        const int2 v = e8tmp[base0 + i];
        const int dstl = v.x >> 20;
        const unsigned src = (unsigned)(v.x & 0xFFFFF);
        __half hw = __float2half_rn(__int_as_float(v.y));
        const unsigned h16 = (unsigned)(*reinterpret_cast<unsigned short*>(&hw)) & 0x7FFFu;
        const int pos = atomicAdd(&woff[dstl], 1);
        e4[base0 + pos] = (src << 15) | h16;
    }
}

// ---- initial fp32 -> fp16 conversion of x0, quarter-split layout [4][NNODES][8 feats] ----
__global__ void cvt_kernel(const float* __restrict__ x, __half* __restrict__ xh) {
    const int i = blockIdx.x * 256 + threadIdx.x;   // over NF/4
    const float4 v = reinterpret_cast<const float4*>(x)[i];
    const int node = i >> 3;
    const int q8 = i & 7;          // 4-feat group
    const int q = q8 >> 1;         // feature quarter
    const int part = q8 & 1;       // 8B half of the 16B quarter row
    __half2 h01 = __floats2half2_rn(v.x, v.y);
    __half2 h23 = __floats2half2_rn(v.z, v.w);
    *reinterpret_cast<uint2*>((char*)xh + (size_t)q * (NNODES * 16) + node * 16 + part * 8)
        = make_uint2(*(unsigned*)&h01, *(unsigned*)&h23);
}

// ---- gather V7: XCD-pinned feature-QUARTER split ----
// bid&7 = XCD r: quarter q = r>>1, node-half hs = r&1.
// Per-XCD L2 working set = 1.6 MB read + 1.6 MB write = 3.2 MB < 4 MB L2 (no thrash).
// lane = nq(3) | slot(3): 8 nodes x 8 edge slots; ONE 16B load per edge (all 8 quarter-feats).
// e4 entry: src<<15 | fp16(w)[14:0]. Quarter-row byte offset = (v>>11) & ~15 = src<<4.
__global__ void gather_kernel(const __half* __restrict__ xh,
                              const int* __restrict__ row_ptr,
                              const unsigned* __restrict__ e4,
                              const float* __restrict__ S,
                              float* __restrict__ out,       // non-null only on last iter
                              __half* __restrict__ outh) {
    const int bid = blockIdx.x;
    const int r = bid & 7;
    const int q = r >> 1;                         // feature quarter 0..3
    const int hs = r & 1;                         // node half
    const int blkl = bid >> 3;                    // [0, 1563)
    const int lane = threadIdx.x & 63;
    const int wid = threadIdx.x >> 6;
    const int nq   = lane >> 3;                   // node index in wave 0..7
    const int slot = lane & 7;                    // edge slot 0..7
    const int lid = blkl * 32 + wid * 8 + nq;     // local node id within half
    if (lid >= 50000) return;                     // partial last block (8-lane groups exit whole)
    const int node = hs * 50000 + lid;
    const int beg = row_ptr[node];
    const int end = row_ptr[node + 1];
    const char* xhc = (const char*)xh + (size_t)q * (NNODES * 16);

    float a0=0.f,a1=0.f,a2=0.f,a3=0.f,a4=0.f,a5=0.f,a6=0.f,a7=0.f;
    const int em1c = (end - 1 > beg) ? (end - 1) : beg;   // safe clamp index
    for (int i = beg + slot; __any(i < end); i += 8) {
        const bool valid = (i < end);
        const unsigned v = e4[valid ? i : em1c];
        unsigned short w16 = (unsigned short)(v & 0x7FFFu);
        const float wv = __half2float(*reinterpret_cast<const __half*>(&w16));
        const float w = valid ? wv : 0.0f;
        const uint4 hv = *reinterpret_cast<const uint4*>(
            xhc + (size_t)((v >> 11) & 0xFFFFF0u));
        float2 f;
        f = __half22float2(*(const __half2*)&hv.x); a0 = fmaf(w, f.x, a0); a1 = fmaf(w, f.y, a1);
        f = __half22float2(*(const __half2*)&hv.y); a2 = fmaf(w, f.x, a2); a3 = fmaf(w, f.y, a3);
        f = __half22float2(*(const __half2*)&hv.z); a4 = fmaf(w, f.x, a4); a5 = fmaf(w, f.y, a5);
        f = __half22float2(*(const __half2*)&hv.w); a6 = fmaf(w, f.x, a6); a7 = fmaf(w, f.y, a7);
    }
    // reduce across the 8 edge slots (lane bits 0..2): xor offsets 1, 2, 4
    #pragma unroll
    for (int off = 1; off <= 4; off <<= 1) {
        a0 += __shfl_xor(a0, off); a1 += __shfl_xor(a1, off);
        a2 += __shfl_xor(a2, off); a3 += __shfl_xor(a3, off);
        a4 += __shfl_xor(a4, off); a5 += __shfl_xor(a5, off);
        a6 += __shfl_xor(a6, off); a7 += __shfl_xor(a7, off);
    }
    if ((lane & 7) == 0) {   // slot == 0 lanes: one per node (8 lanes)
        // self term from fp16 (8 quarter-feats)
        const uint4 hx = *reinterpret_cast<const uint4*>(xhc + node * 16);
        float2 f;
        f = __half22float2(*(const __half2*)&hx.x); const float x0f = f.x, x1f = f.y;
        f = __half22float2(*(const __half2*)&hx.y); const float x2f = f.x, x3f = f.y;
        f = __half22float2(*(const __half2*)&hx.z); const float x4f = f.x, x5f = f.y;
        f = __half22float2(*(const __half2*)&hx.w); const float x6f = f.x, x7f = f.y;
        if (node == 0) {   // masked-edge bulk contribution
            const float S0 = *S;
            a0 = fmaf(S0, x0f, a0); a1 = fmaf(S0, x1f, a1);
            a2 = fmaf(S0, x2f, a2); a3 = fmaf(S0, x3f, a3);
            a4 = fmaf(S0, x4f, a4); a5 = fmaf(S0, x5f, a5);
            a6 = fmaf(S0, x6f, a6); a7 = fmaf(S0, x7f, a7);
        }
        const float r0 = fminf(fmaxf(x0f + fminf(fmaxf(a0 - x0f, -1.f), 1.f), 0.f), 2.f);
        const float r1 = fminf(fmaxf(x1f + fminf(fmaxf(a1 - x1f, -1.f), 1.f), 0.f), 2.f);
        const float r2 = fminf(fmaxf(x2f + fminf(fmaxf(a2 - x2f, -1.f), 1.f), 0.f), 2.f);
        const float r3 = fminf(fmaxf(x3f + fminf(fmaxf(a3 - x3f, -1.f), 1.f), 0.f), 2.f);
        const float r4 = fminf(fmaxf(x4f + fminf(fmaxf(a4 - x4f, -1.f), 1.f), 0.f), 2.f);
        const float r5 = fminf(fmaxf(x5f + fminf(fmaxf(a5 - x5f, -1.f), 1.f), 0.f), 2.f);
        const float r6 = fminf(fmaxf(x6f + fminf(fmaxf(a6 - x6f, -1.f), 1.f), 0.f), 2.f);
        const float r7 = fminf(fmaxf(x7f + fminf(fmaxf(a7 - x7f, -1.f), 1.f), 0.f), 2.f);
        __half2 h0 = __floats2half2_rn(r0, r1);
        __half2 h1 = __floats2half2_rn(r2, r3);
        __half2 h2 = __floats2half2_rn(r4, r5);
        __half2 h3 = __floats2half2_rn(r6, r7);
        uint4 hh;
        hh.x = *(unsigned*)&h0; hh.y = *(unsigned*)&h1;
        hh.z = *(unsigned*)&h2; hh.w = *(unsigned*)&h3;
        *reinterpret_cast<uint4*>((char*)outh + (size_t)q * (NNODES * 16) + node * 16) = hh;
        if (out) {
            float* op = out + node * FEAT + (q << 3);
            *reinterpret_cast<float4*>(op)     = make_float4(r0, r1, r2, r3);
            *reinterpret_cast<float4*>(op + 4) = make_float4(r4, r5, r6, r7);
        }
    }
}

extern "C" void kernel_launch(void* const* d_in, const int* in_sizes, int n_in,
                              void* d_out, int out_size, void* d_ws, size_t ws_size,
                              hipStream_t stream) {
    const float* x0         = (const float*)d_in[0];
    const int*   edge_index = (const int*)d_in[1];
    const int*   edge_mask  = (const int*)d_in[2];
    const float* edge_scale = (const float*)d_in[3];
    const float* pert_mask  = (const float*)d_in[4];
    const float* edge_weight= (const float*)d_in[5];
    float* xout = (float*)d_out;

    // ---- workspace layout (time-multiplexed) ----
    // [0, 64K)       S, S_part (782 floats)
    // [64K, 480K)    tb/tboff/bbase/row_ptr
    // [1M, 2.25M)    M
    // [3M, 4.25M)    scanT                       (dead after fill782)
    // [5M, 17.8M)    e8tmp (12.8 MB)             (dead after bsort)
    // [18M, 24.4M)   e4 (6.4 MB)                 (live all gathers)
    // [25M, 50.6M)   pay (25.6 MB)               (dead after fill782)
    //   -> xh0 [25M, 31.4M), xh1 [32M, 38.4M)    (written by cvt/gather, after fill782)
    // [51M, 57.4M)   bkt (6.4 MB)                (dead after fill782)
    char* ws = (char*)d_ws;
    float* S        = (float*)(ws);                          // 4 B
    float* S_part   = (float*)(ws + 1024);                   // 782 floats
    int*   tb       = (int*)(ws + 64 * 1024);                // 299 ints
    int*   tboff    = (int*)(ws + 68 * 1024);                // 299 ints
    int*   bbase    = (int*)(ws + 72 * 1024);                // 392 ints
    int*   row_ptr  = (int*)(ws + 80 * 1024);                // 100001 ints
    int*   M        = (int*)(ws + 1  * 1024 * 1024);         // NT ints (1.22 MB)
    int*   scanT    = (int*)(ws + 3  * 1024 * 1024);         // NT ints (1.22 MB)
    int2*  e8tmp    = (int2*)(ws + 5  * 1024 * 1024);        // ~12.8 MB used
    unsigned* e4    = (unsigned*)(ws + 18 * 1024 * 1024);    // ~6.4 MB used
    int2*  pay      = (int2*)(ws + 25 * 1024 * 1024);        // 25.6 MB
    unsigned short* bkt = (unsigned short*)(ws + 51 * 1024 * 1024);  // 6.4 MB
    __half* xh0     = (__half*)(ws + 25 * 1024 * 1024);      // 6.4 MB, aliases dead pay
    __half* xh1     = (__half*)(ws + 32 * 1024 * 1024);      // 6.4 MB, aliases dead pay

    ws_kernel<<<NBF, 256, 0, stream>>>(edge_index, edge_mask, edge_scale,
                                       pert_mask, edge_weight, pay, bkt, M, S_part);
    sreduce_kernel<<<1, 1024, 0, stream>>>(S_part, S);
    tscan1_kernel<<<NTB, 1024, 0, stream>>>(M, tb);
    tscan2_kernel<<<1, 512, 0, stream>>>(tb, tboff, bbase);
    tscan3_kernel<<<NTB, 1024, 0, stream>>>(M, tboff, scanT, bbase);
    fill782_kernel<<<NBF, 256, 0, stream>>>(pay, bkt, scanT, e8tmp);
    bsort_kernel<<<NBK, 256, 0, stream>>>(e8tmp, bbase, e4, row_ptr);
    cvt_kernel<<<NF / 4 / 256, 256, 0, stream>>>(x0, xh0);   // 3125 blocks, exact

    // 5 gather iterations entirely in fp16 ping-pong; fp32 out written on last iter only
    const int gblocks = 12504;   // 1563*8: 4 quarters x 2 node-halves, 32 nodes/block
    __half* xhb[2] = { xh0, xh1 };
    for (int it = 0; it < NITER; ++it) {
        gather_kernel<<<gblocks, 256, 0, stream>>>(xhb[it & 1], row_ptr, e4, S,
                                                   (it == NITER - 1) ? xout : nullptr,
                                                   xhb[(it + 1) & 1]);
    }
}

// Round 18
// 214.586 us; speedup vs baseline: 1.2007x; 1.2007x over previous
//
#include <hip/hip_runtime.h>
#include <hip/hip_fp16.h>

#define NNODES 100000
#define NEDGES 3200000
#define FEAT 32
#define NITER 5
#define NF (NNODES * FEAT)

// bucket partition
#define BUCK_SH 8
#define BUCK_SZ 256                    // dsts per bucket
#define NBK 391                        // ceil(100000/256)
#define CHUNKF 4096                    // edges per ws/fill block
#define NBF 782                        // 782*4096 = 3,203,072 >= NEDGES
#define NT (NBF * NBK)                 // 305,762 matrix elements
#define NTB 299                        // ceil(NT/1024)

// ---- pass A (fused): packed payload + bucket id + per-block histogram + masked-sum ----
// pay[e] = (src | dstl<<20, w_bits); bkt[e] = dst>>8 (0xFFFF if masked); M[b*NBK+k] = count
__global__ void ws_kernel(const int* __restrict__ edge_index,
                          const int* __restrict__ edge_mask,
                          const float* __restrict__ edge_scale,
                          const float* __restrict__ pert_mask,
                          const float* __restrict__ edge_weight,
                          int2* __restrict__ pay,
                          unsigned short* __restrict__ bkt,
                          int* __restrict__ M,
                          float* __restrict__ S_part) {
    __shared__ int h[NBK];
    __shared__ float sred[256];
    const int b = blockIdx.x;
    for (int k = threadIdx.x; k < NBK; k += 256) h[k] = 0;
    __syncthreads();
    const int base = b * CHUNKF;
    float ms = 0.0f;
    for (int it = 0; it < CHUNKF / 256; ++it) {
        const int e = base + it * 256 + threadIdx.x;
        if (e < NEDGES) {
            const int m = edge_mask[e];
            const float w = (edge_weight[e] * (1.0f - pert_mask[e]) + pert_mask[e]) * edge_scale[e];
            const int src = edge_index[e];
            const int dst = edge_index[NEDGES + e];
            pay[e] = make_int2(src | ((dst & (BUCK_SZ - 1)) << 20), __float_as_int(w));
            if (m) {
                bkt[e] = (unsigned short)(dst >> BUCK_SH);
                atomicAdd(&h[dst >> BUCK_SH], 1);
            } else {
                bkt[e] = (unsigned short)0xFFFFu;
                ms += w;
            }
        }
    }
    sred[threadIdx.x] = ms;
    __syncthreads();                      // also orders all h[] atomics before M write
    for (int off = 128; off; off >>= 1) {
        if (threadIdx.x < off) sred[threadIdx.x] += sred[threadIdx.x + off];
        __syncthreads();
    }
    if (threadIdx.x == 0) S_part[b] = sred[0];
    for (int k = threadIdx.x; k < NBK; k += 256) M[b * NBK + k] = h[k];
}

__global__ void sreduce_kernel(const float* __restrict__ S_part, float* __restrict__ S) {
    __shared__ float s[1024];
    float a = 0.0f;
    for (int i = threadIdx.x; i < NBF; i += 1024) a += S_part[i];
    s[threadIdx.x] = a;
    __syncthreads();
    for (int off = 512; off; off >>= 1) {
        if (threadIdx.x < off) s[threadIdx.x] += s[threadIdx.x + off];
        __syncthreads();
    }
    if (threadIdx.x == 0) *S = s[0];
}

// ---- 3-stage exclusive scan over M in bucket-major (transposed) order ----
__global__ void tscan1_kernel(const int* __restrict__ M, int* __restrict__ tb) {
    __shared__ int s[1024];
    const int i = blockIdx.x * 1024 + threadIdx.x;
    int v = 0;
    if (i < NT) v = M[(i % NBF) * NBK + (i / NBF)];
    s[threadIdx.x] = v;
    __syncthreads();
    for (int off = 512; off; off >>= 1) {
        if (threadIdx.x < off) s[threadIdx.x] += s[threadIdx.x + off];
        __syncthreads();
    }
    if (threadIdx.x == 0) tb[blockIdx.x] = s[0];
}

__global__ void tscan2_kernel(const int* __restrict__ tb, int* __restrict__ tboff,
                              int* __restrict__ bucket_base) {
    __shared__ int s[512];
    const int tid = threadIdx.x;
    int v = (tid < NTB) ? tb[tid] : 0;
    s[tid] = v;
    __syncthreads();
    for (int off = 1; off < 512; off <<= 1) {
        int t = (tid >= off) ? s[tid - off] : 0;
        __syncthreads();
        s[tid] += t;
        __syncthreads();
    }
    if (tid < NTB) tboff[tid] = s[tid] - v;     // exclusive
    if (tid == 511) bucket_base[NBK] = s[511];  // total unmasked edges
}

__global__ void tscan3_kernel(const int* __restrict__ M, const int* __restrict__ tboff,
                              int* __restrict__ scanT, int* __restrict__ bucket_base) {
    __shared__ int s[1024];
    const int tid = threadIdx.x;
    const int i = blockIdx.x * 1024 + tid;
    int v = 0;
    if (i < NT) v = M[(i % NBF) * NBK + (i / NBF)];
    s[tid] = v;
    __syncthreads();
    for (int off = 1; off < 1024; off <<= 1) {
        int t = (tid >= off) ? s[tid - off] : 0;
        __syncthreads();
        s[tid] += t;
        __syncthreads();
    }
    if (i < NT) {
        const int excl = tboff[blockIdx.x] + s[tid] - v;
        scanT[i] = excl;
        if (i % NBF == 0) bucket_base[i / NBF] = excl;
    }
}

// ---- fill: scatter packed payload to matrix offsets; no global atomics ----
__global__ void fill782_kernel(const int2* __restrict__ pay,
                               const unsigned short* __restrict__ bkt,
                               const int* __restrict__ scanT,
                               int2* __restrict__ e8tmp) {
    __shared__ int off[NBK];
    const int b = blockIdx.x;
    for (int k = threadIdx.x; k < NBK; k += 256) off[k] = scanT[k * NBF + b];
    __syncthreads();
    const int base = b * CHUNKF;
    for (int it = 0; it < CHUNKF / 256; ++it) {
        const int e = base + it * 256 + threadIdx.x;
        if (e < NEDGES) {
            const unsigned short k = bkt[e];
            if (k != 0xFFFFu) {
                const int pos = atomicAdd(&off[k], 1);
                e8tmp[pos] = pay[e];
            }
        }
    }
}

// ---- bucket sort: one block per bucket; LDS counting sort by local dst ----
// emits final dst-sorted PACKED e4 (src<<15 | fp16(w) sans sign) and row_ptr.
// w >= 0 always ((ew*(1-pm)+pm)*es, all operands in [0,1)) so the sign bit is free.
__global__ void bsort_kernel(const int2* __restrict__ e8tmp,
                             const int* __restrict__ bucket_base,
                             unsigned* __restrict__ e4,
                             int* __restrict__ row_ptr) {
    __shared__ int h[BUCK_SZ];
    __shared__ int s[BUCK_SZ];
    __shared__ int woff[BUCK_SZ];
    const int k = blockIdx.x;
    const int tid = threadIdx.x;
    const int base0 = bucket_base[k];
    const int cnt = bucket_base[k + 1] - base0;
    h[tid] = 0;
    __syncthreads();
    for (int i = tid; i < cnt; i += 256) {
        const int dstl = e8tmp[base0 + i].x >> 20;   // bits 20..27 (src < 2^17)
        atomicAdd(&h[dstl], 1);
    }
    __syncthreads();
    s[tid] = h[tid];
    __syncthreads();
    for (int off = 1; off < BUCK_SZ; off <<= 1) {
        int t = (tid >= off) ? s[tid - off] : 0;
        __syncthreads();
        s[tid] += t;
        __syncthreads();
    }
    {
        const int excl = s[tid] - h[tid];
        const int d = k * BUCK_SZ + tid;
        if (d < NNODES) row_ptr[d] = base0 + excl;
        woff[tid] = excl;
    }
    if (k == NBK - 1 && tid == 0) row_ptr[NNODES] = bucket_base[NBK];
    __syncthreads();
    for (int i = tid; i < cnt; i += 256) {
        const int2 v = e8tmp[base0 + i];
        const int dstl = v.x >> 20;
        const unsigned src = (unsigned)(v.x & 0xFFFFF);
        __half hw = __float2half_rn(__int_as_float(v.y));
        const unsigned h16 = (unsigned)(*reinterpret_cast<unsigned short*>(&hw)) & 0x7FFFu;
        const int pos = atomicAdd(&woff[dstl], 1);
        e4[base0 + pos] = (src << 15) | h16;
    }
}

// ---- initial fp32 -> fp16 conversion of x0, split-half layout [2][NNODES][16] ----
__global__ void cvt_kernel(const float* __restrict__ x, __half* __restrict__ xh) {
    const int i = blockIdx.x * 256 + threadIdx.x;   // over NF/4
    const float4 v = reinterpret_cast<const float4*>(x)[i];
    const int node = i >> 3;
    const int q = i & 7;           // quarter-row: feats [q*4, q*4+4)
    const int fh = q >> 2;
    const int part = q & 3;
    __half2 h01 = __floats2half2_rn(v.x, v.y);
    __half2 h23 = __floats2half2_rn(v.z, v.w);
    *reinterpret_cast<uint2*>((char*)xh + (size_t)fh * (NNODES * 32) + node * 32 + part * 8)
        = make_uint2(*(unsigned*)&h01, *(unsigned*)&h23);
}

// ---- gather V6 (the proven best): XCD-pinned feature-HALF split, 8 nodes/wave ----
// bid&7 = XCD: XCDs 0-3 -> feat half 0, 4-7 -> half 1 (per-XCD xh footprint 3.2 MB).
// lane = nq(3) | slot(2) | part(1): 8 nodes x 4 edge slots x 2x16B parts -> 25K waves.
// e4 entry: src<<15 | fp16(w)[14:0]. Byte offset = (v>>10) & ~31.
__global__ void gather_kernel(const __half* __restrict__ xh,
                              const int* __restrict__ row_ptr,
                              const unsigned* __restrict__ e4,
                              const float* __restrict__ S,
                              float* __restrict__ out,       // non-null only on last iter
                              __half* __restrict__ outh) {
    const int bid = blockIdx.x;
    const int r = bid & 7;
    const int fh = r >> 2;                        // feature half
    const int blk = (bid >> 3) * 4 + (r & 3);     // [0, 3128)
    if (blk >= 3125) return;                      // 3125*32 = 100000 exactly
    const int lane = threadIdx.x & 63;
    const int wid = threadIdx.x >> 6;
    const int nq   = lane >> 3;                   // node index in wave 0..7
    const int slot = (lane >> 1) & 3;             // edge slot 0..3
    const int part = lane & 1;                    // 16B part of the 32B half-row
    const int node = blk * 32 + wid * 8 + nq;
    const int beg = row_ptr[node];
    const int end = row_ptr[node + 1];
    const char* xhc = (const char*)xh + (size_t)fh * (NNODES * 32);

    float a0=0.f,a1=0.f,a2=0.f,a3=0.f,a4=0.f,a5=0.f,a6=0.f,a7=0.f;
    const int em1c = (end - 1 > beg) ? (end - 1) : beg;   // safe clamp index
    for (int i = beg + slot; __any(i < end); i += 4) {
        const bool valid = (i < end);
        const unsigned v = e4[valid ? i : em1c];
        unsigned short w16 = (unsigned short)(v & 0x7FFFu);
        const float wv = __half2float(*reinterpret_cast<const __half*>(&w16));
        const float w = valid ? wv : 0.0f;
        const uint4 hv = *reinterpret_cast<const uint4*>(
            xhc + (size_t)((v >> 10) & 0xFFFFE0u) + (part << 4));
        float2 f;
        f = __half22float2(*(const __half2*)&hv.x); a0 = fmaf(w, f.x, a0); a1 = fmaf(w, f.y, a1);
        f = __half22float2(*(const __half2*)&hv.y); a2 = fmaf(w, f.x, a2); a3 = fmaf(w, f.y, a3);
        f = __half22float2(*(const __half2*)&hv.z); a4 = fmaf(w, f.x, a4); a5 = fmaf(w, f.y, a5);
        f = __half22float2(*(const __half2*)&hv.w); a6 = fmaf(w, f.x, a6); a7 = fmaf(w, f.y, a7);
    }
    // reduce across the 4 edge slots (lane bits 1..2): xor offsets 2, 4
    #pragma unroll
    for (int off = 2; off <= 4; off <<= 1) {
        a0 += __shfl_xor(a0, off); a1 += __shfl_xor(a1, off);
        a2 += __shfl_xor(a2, off); a3 += __shfl_xor(a3, off);
        a4 += __shfl_xor(a4, off); a5 += __shfl_xor(a5, off);
        a6 += __shfl_xor(a6, off); a7 += __shfl_xor(a7, off);
    }
    if ((lane & 6) == 0) {   // slot == 0 lanes: {nq, part} (16 lanes)
        // self term from fp16 (8 feats)
        const uint4 hx = *reinterpret_cast<const uint4*>(xhc + node * 32 + (part << 4));
        float2 f;
        f = __half22float2(*(const __half2*)&hx.x); const float x0f = f.x, x1f = f.y;
        f = __half22float2(*(const __half2*)&hx.y); const float x2f = f.x, x3f = f.y;
        f = __half22float2(*(const __half2*)&hx.z); const float x4f = f.x, x5f = f.y;
        f = __half22float2(*(const __half2*)&hx.w); const float x6f = f.x, x7f = f.y;
        if (node == 0) {   // masked-edge bulk contribution
            const float S0 = *S;
            a0 = fmaf(S0, x0f, a0); a1 = fmaf(S0, x1f, a1);
            a2 = fmaf(S0, x2f, a2); a3 = fmaf(S0, x3f, a3);
            a4 = fmaf(S0, x4f, a4); a5 = fmaf(S0, x5f, a5);
            a6 = fmaf(S0, x6f, a6); a7 = fmaf(S0, x7f, a7);
        }
        const float r0 = fminf(fmaxf(x0f + fminf(fmaxf(a0 - x0f, -1.f), 1.f), 0.f), 2.f);
        const float r1 = fminf(fmaxf(x1f + fminf(fmaxf(a1 - x1f, -1.f), 1.f), 0.f), 2.f);
        const float r2 = fminf(fmaxf(x2f + fminf(fmaxf(a2 - x2f, -1.f), 1.f), 0.f), 2.f);
        const float r3 = fminf(fmaxf(x3f + fminf(fmaxf(a3 - x3f, -1.f), 1.f), 0.f), 2.f);
        const float r4 = fminf(fmaxf(x4f + fminf(fmaxf(a4 - x4f, -1.f), 1.f), 0.f), 2.f);
        const float r5 = fminf(fmaxf(x5f + fminf(fmaxf(a5 - x5f, -1.f), 1.f), 0.f), 2.f);
        const float r6 = fminf(fmaxf(x6f + fminf(fmaxf(a6 - x6f, -1.f), 1.f), 0.f), 2.f);
        const float r7 = fminf(fmaxf(x7f + fminf(fmaxf(a7 - x7f, -1.f), 1.f), 0.f), 2.f);
        __half2 h0 = __floats2half2_rn(r0, r1);
        __half2 h1 = __floats2half2_rn(r2, r3);
        __half2 h2 = __floats2half2_rn(r4, r5);
        __half2 h3 = __floats2half2_rn(r6, r7);
        uint4 hh;
        hh.x = *(unsigned*)&h0; hh.y = *(unsigned*)&h1;
        hh.z = *(unsigned*)&h2; hh.w = *(unsigned*)&h3;
        *reinterpret_cast<uint4*>((char*)outh + (size_t)fh * (NNODES * 32)
                                  + node * 32 + (part << 4)) = hh;
        if (out) {
            float* op = out + node * FEAT + (fh << 4) + (part << 3);
            *reinterpret_cast<float4*>(op)     = make_float4(r0, r1, r2, r3);
            *reinterpret_cast<float4*>(op + 4) = make_float4(r4, r5, r6, r7);
        }
    }
}

extern "C" void kernel_launch(void* const* d_in, const int* in_sizes, int n_in,
                              void* d_out, int out_size, void* d_ws, size_t ws_size,
                              hipStream_t stream) {
    const float* x0         = (const float*)d_in[0];
    const int*   edge_index = (const int*)d_in[1];
    const int*   edge_mask  = (const int*)d_in[2];
    const float* edge_scale = (const float*)d_in[3];
    const float* pert_mask  = (const float*)d_in[4];
    const float* edge_weight= (const float*)d_in[5];
    float* xout = (float*)d_out;

    // ---- workspace layout (time-multiplexed) ----
    // [0, 64K)       S, S_part (782 floats)
    // [64K, 480K)    tb/tboff/bbase/row_ptr
    // [1M, 2.25M)    M
    // [3M, 4.25M)    scanT                       (dead after fill782)
    // [5M, 17.8M)    e8tmp (12.8 MB)             (dead after bsort)
    // [18M, 24.4M)   e4 (6.4 MB)                 (live all gathers)
    // [25M, 50.6M)   pay (25.6 MB)               (dead after fill782)
    //   -> xh0 [25M, 31.4M), xh1 [32M, 38.4M)    (written by cvt/gather, after fill782)
    // [51M, 57.4M)   bkt (6.4 MB)                (dead after fill782)
    char* ws = (char*)d_ws;
    float* S        = (float*)(ws);                          // 4 B
    float* S_part   = (float*)(ws + 1024);                   // 782 floats
    int*   tb       = (int*)(ws + 64 * 1024);                // 299 ints
    int*   tboff    = (int*)(ws + 68 * 1024);                // 299 ints
    int*   bbase    = (int*)(ws + 72 * 1024);                // 392 ints
    int*   row_ptr  = (int*)(ws + 80 * 1024);                // 100001 ints
    int*   M        = (int*)(ws + 1  * 1024 * 1024);         // NT ints (1.22 MB)
    int*   scanT    = (int*)(ws + 3  * 1024 * 1024);         // NT ints (1.22 MB)
    int2*  e8tmp    = (int2*)(ws + 5  * 1024 * 1024);        // ~12.8 MB used
    unsigned* e4    = (unsigned*)(ws + 18 * 1024 * 1024);    // ~6.4 MB used
    int2*  pay      = (int2*)(ws + 25 * 1024 * 1024);        // 25.6 MB
    unsigned short* bkt = (unsigned short*)(ws + 51 * 1024 * 1024);  // 6.4 MB
    __half* xh0     = (__half*)(ws + 25 * 1024 * 1024);      // 6.4 MB, aliases dead pay
    __half* xh1     = (__half*)(ws + 32 * 1024 * 1024);      // 6.4 MB, aliases dead pay

    ws_kernel<<<NBF, 256, 0, stream>>>(edge_index, edge_mask, edge_scale,
                                       pert_mask, edge_weight, pay, bkt, M, S_part);
    sreduce_kernel<<<1, 1024, 0, stream>>>(S_part, S);
    tscan1_kernel<<<NTB, 1024, 0, stream>>>(M, tb);
    tscan2_kernel<<<1, 512, 0, stream>>>(tb, tboff, bbase);
    tscan3_kernel<<<NTB, 1024, 0, stream>>>(M, tboff, scanT, bbase);
    fill782_kernel<<<NBF, 256, 0, stream>>>(pay, bkt, scanT, e8tmp);
    bsort_kernel<<<NBK, 256, 0, stream>>>(e8tmp, bbase, e4, row_ptr);
    cvt_kernel<<<NF / 4 / 256, 256, 0, stream>>>(x0, xh0);   // 3125 blocks, exact

    // 5 gather iterations entirely in fp16 ping-pong; fp32 out written on last iter only
    const int gblocks = 6256;   // 782*8: both halves, 32 nodes/block, 3 tail node-blocks idle
    __half* xhb[2] = { xh0, xh1 };
    for (int it = 0; it < NITER; ++it) {
        gather_kernel<<<gblocks, 256, 0, stream>>>(xhb[it & 1], row_ptr, e4, S,
                                                   (it == NITER - 1) ? xout : nullptr,
                                                   xhb[(it + 1) & 1]);
    }
}